// Round 1
// 417.577 us; speedup vs baseline: 1.0078x; 1.0078x over previous
//
#include <hip/hip_runtime.h>
#include <cstdint>

// SpikeFP64Sqrt: rows of 64 float pulses (MSB-first fp64 bits) -> sqrt via
// exponent-halving guess + 12 IEEE fp64 Newton iterations -> pulses out.
//
// R8: re-fused single kernel. Rationale: R7's pure-stream split measured the
// SAME dur as the R6 fused kernel (~420 total) -> the "mixed stream" theory
// is dead; the common tax is (a) the poison-dirty L3 (1GiB fill right before
// us) forcing victim writebacks when input reads allocate, (b) the split's
// extra launch/drain + 16MiB words round-trip. Fix: one kernel, registers
// only, nontemporal on BOTH streams: nt loads (read-once input, evict-first
// so input allocations mostly evict each other, not dirty poison) and nt
// STORES (new: coherently hit/update the dirty poison lines for the output
// region and mark them evict-first -> no extra output double-write).
// Predict: kernel ~90-120us, dur 420 -> ~360-390. Flat dur => harness floor.

#pragma clang fp contract(off)   // no FMA contraction anywhere (bit-exact fp64)

typedef float f32x4 __attribute__((ext_vector_type(4)));

static constexpr uint64_t kSqrt2Mant = 1865452045155277ULL;
static constexpr uint64_t kNanBits   = 0x7FF8000000000000ULL;
static constexpr uint64_t kInfBits   = 0x7FF0000000000000ULL;
static constexpr uint64_t kMantMask  = 0xFFFFFFFFFFFFFULL;

__global__ __launch_bounds__(256) void spike_sqrt_fused_kernel(
    const float* __restrict__ x, float* __restrict__ out, int rows) {
  const int lane   = threadIdx.x & 63;
  const int waveId = (int)blockIdx.x * 4 + (threadIdx.x >> 6);
  const long long waveRow0 = (long long)waveId * 64;
  const int col = lane ^ 63;   // lane j reads pulse (63-j): ballot bit j == MSB-first bit j

  // ---- pack: 64 rows -> one u64 per lane (lane L holds row waveRow0+L) ----
  uint64_t u = 0;
  const bool fullWave = (waveRow0 + 64) <= (long long)rows;
  if (fullWave) {
    const float* base = x + waveRow0 * 64 + col;
#pragma unroll
    for (int b = 0; b < 2; ++b) {
      float v[32];
#pragma unroll
      for (int k = 0; k < 32; ++k)   // 32 nt loads in flight (read-once stream)
        v[k] = __builtin_nontemporal_load(base + (size_t)(b * 32 + k) * 64);
#pragma unroll
      for (int k = 0; k < 32; ++k) {
        unsigned long long m = __ballot(v[k] > 0.5f);
        if (lane == b * 32 + k) u = m;
      }
    }
  } else {
#pragma unroll 4
    for (int rr = 0; rr < 64; ++rr) {
      const long long row = waveRow0 + rr;
      float v = (row < (long long)rows) ? x[row * 64 + col] : 0.0f;
      unsigned long long m = __ballot(v > 0.5f);
      if (lane == rr) u = m;
    }
  }

  // ---- per-lane fp64 sqrt, bit-exact vs reference ----
  const double f = __longlong_as_double((long long)u);

  const int e_x    = (int)((u >> 52) & 0x7FF);
  const int e_real = e_x - 1023;                       // 11-bit two's complement
  const long long e_half = ((long long)e_real) >> 1;   // arithmetic shift = floor/2
  const uint64_t mant = ((e_real & 1) != 0) ? kSqrt2Mant : 0ULL;
  const uint64_t ybits = (((uint64_t)(e_half + 1023)) << 52) | mant;
  double y = __longlong_as_double((long long)ybits);

#pragma unroll
  for (int it = 0; it < 12; ++it) {
    y = 0.5 * (y + f / y);                             // IEEE fp64, no contraction
  }

  uint64_t r = (uint64_t)__double_as_longlong(y);
  const bool is_neg    = (u >> 63) != 0;
  const bool m_any     = (u & kMantMask) != 0;
  const bool e_all_one = (e_x == 0x7FF);
  const bool e_is_zero = (e_x == 0);
  if (is_neg) r = kNanBits;                            // same override order as ref
  if (e_all_one && m_any) r = kNanBits;
  if (e_all_one && !m_any && !is_neg) r = kInfBits;
  if (e_is_zero && !m_any) r = 0ULL;

  // ---- unpack straight from registers (shfl), nt f32x4 stores ----
  const long long rl = (long long)r;
#pragma unroll
  for (int t = 0; t < 16; ++t) {
    const int srcRow = 4 * t + (lane >> 4);            // 0..63 within the wave
    const uint64_t b = (uint64_t)__shfl(rl, srcRow, 64);
    const int c0 = (lane & 15) * 4;                    // pulse index of o.x
    f32x4 o;
    o.x = (float)((b >> (63 - c0)) & 1ULL);
    o.y = (float)((b >> (62 - c0)) & 1ULL);
    o.z = (float)((b >> (61 - c0)) & 1ULL);
    o.w = (float)((b >> (60 - c0)) & 1ULL);
    const long long row = waveRow0 + srcRow;
    if (row < (long long)rows) {
      // 1KB contiguous per instr (full 128B lines), non-temporal: hit the
      // poison-dirty L3 lines in place, evict-first.
      __builtin_nontemporal_store(o, reinterpret_cast<f32x4*>(out + row * 64 + c0));
    }
  }
}

extern "C" void kernel_launch(void* const* d_in, const int* in_sizes, int n_in,
                              void* d_out, int out_size, void* d_ws, size_t ws_size,
                              hipStream_t stream) {
  const float* x = (const float*)d_in[0];
  float* out = (float*)d_out;
  (void)d_ws; (void)ws_size;
  const int rows = in_sizes[0] / 64;                   // 64 pulses per fp64
  const int rowsPerBlock = 256;                        // 4 waves * 64 rows
  const int grid = (rows + rowsPerBlock - 1) / rowsPerBlock;
  spike_sqrt_fused_kernel<<<grid, 256, 0, stream>>>(x, out, rows);
}

// Round 2
// 416.131 us; speedup vs baseline: 1.0113x; 1.0035x over previous
//
#include <hip/hip_runtime.h>
#include <cstdint>

// SpikeFP64Sqrt: rows of 64 float pulses (MSB-first fp64 bits) -> sqrt via
// exponent-halving guess + 12 IEEE fp64 Newton iterations -> pulses out.
//
// R9: vectorized READ side. R8 post-mortem: nt stores changed nothing; dur
// pinned ~418-421 across split/fused/nt variants. The one shared untouched
// piece: scalar dword input loads (256B/wave/instr) vs dwordx4 stores
// (1KB/wave/instr). G13: scalar loads run ~2x under the float4 copy ceiling
// -> read side ~4 TB/s is the residual tax. Fix: f32x4 loads (16 per wave,
// all prefetched), per-lane nibble pack, 4x shfl_xor u64 OR-reduce within
// 16-lane groups, 1 shfl capture so lane L ends with row waveRow0+L.
// Predict: kernel ~145 -> ~100-115us, dur 417 -> ~370-390. Flat dur again
// => harness floor, call ROOFLINE.

#pragma clang fp contract(off)   // no FMA contraction anywhere (bit-exact fp64)

typedef float f32x4 __attribute__((ext_vector_type(4)));

static constexpr uint64_t kSqrt2Mant = 1865452045155277ULL;
static constexpr uint64_t kNanBits   = 0x7FF8000000000000ULL;
static constexpr uint64_t kInfBits   = 0x7FF0000000000000ULL;
static constexpr uint64_t kMantMask  = 0xFFFFFFFFFFFFFULL;

__global__ __launch_bounds__(256) void spike_sqrt_fused_kernel(
    const float* __restrict__ x, float* __restrict__ out, int rows) {
  const int lane   = threadIdx.x & 63;
  const int waveId = (int)blockIdx.x * 4 + (threadIdx.x >> 6);
  const long long waveRow0 = (long long)waveId * 64;

  // ---- pack: 64 rows -> one u64 per lane (lane L holds row waveRow0+L) ----
  uint64_t u = 0;
  const bool fullWave = (waveRow0 + 64) <= (long long)rows;
  if (fullWave) {
    // Vectorized read: iteration t covers rows 4t..4t+3 (1KB contiguous/wave).
    // lane layout: group g = lane>>4 -> row 4t+g; c0 = (lane&15)*4 = pulse col.
    const f32x4* vbase = reinterpret_cast<const f32x4*>(x) +
                         (waveRow0 * 16 + (long long)(lane >> 4) * 16 + (lane & 15));
    f32x4 v[16];
#pragma unroll
    for (int t = 0; t < 16; ++t)            // 16 nt dwordx4 loads in flight
      v[t] = __builtin_nontemporal_load(vbase + 64 * t);

    const int shift   = 60 - ((lane & 15) << 2);   // nibble bit position (MSB-first)
    const int myT     = lane >> 2;                 // iteration that loads my row
    const int srcLane = (lane & 3) << 4;           // group holding my row
#pragma unroll
    for (int t = 0; t < 16; ++t) {
      const f32x4 p = v[t];
      const uint32_t nib = (p.x > 0.5f ? 8u : 0u) | (p.y > 0.5f ? 4u : 0u) |
                           (p.z > 0.5f ? 2u : 0u) | (p.w > 0.5f ? 1u : 0u);
      uint64_t w = (uint64_t)nib << shift;
      // OR-reduce within each 16-lane group (xor masks 1,2,4,8 stay in-group)
      w |= (uint64_t)__shfl_xor((long long)w, 1, 64);
      w |= (uint64_t)__shfl_xor((long long)w, 2, 64);
      w |= (uint64_t)__shfl_xor((long long)w, 4, 64);
      w |= (uint64_t)__shfl_xor((long long)w, 8, 64);
      // lane L's row (= waveRow0 + L) is row 4t+(L&3), held by group L&3
      const uint64_t sel = (uint64_t)__shfl((long long)w, srcLane, 64);
      if (myT == t) u = sel;
    }
  } else {
    const int col = lane ^ 63;   // ballot bit j == MSB-first bit j
#pragma unroll 4
    for (int rr = 0; rr < 64; ++rr) {
      const long long row = waveRow0 + rr;
      float v = (row < (long long)rows) ? x[row * 64 + col] : 0.0f;
      unsigned long long m = __ballot(v > 0.5f);
      if (lane == rr) u = m;
    }
  }

  // ---- per-lane fp64 sqrt, bit-exact vs reference ----
  const double f = __longlong_as_double((long long)u);

  const int e_x    = (int)((u >> 52) & 0x7FF);
  const int e_real = e_x - 1023;                       // 11-bit two's complement
  const long long e_half = ((long long)e_real) >> 1;   // arithmetic shift = floor/2
  const uint64_t mant = ((e_real & 1) != 0) ? kSqrt2Mant : 0ULL;
  const uint64_t ybits = (((uint64_t)(e_half + 1023)) << 52) | mant;
  double y = __longlong_as_double((long long)ybits);

#pragma unroll
  for (int it = 0; it < 12; ++it) {
    y = 0.5 * (y + f / y);                             // IEEE fp64, no contraction
  }

  uint64_t r = (uint64_t)__double_as_longlong(y);
  const bool is_neg    = (u >> 63) != 0;
  const bool m_any     = (u & kMantMask) != 0;
  const bool e_all_one = (e_x == 0x7FF);
  const bool e_is_zero = (e_x == 0);
  if (is_neg) r = kNanBits;                            // same override order as ref
  if (e_all_one && m_any) r = kNanBits;
  if (e_all_one && !m_any && !is_neg) r = kInfBits;
  if (e_is_zero && !m_any) r = 0ULL;

  // ---- unpack straight from registers (shfl), nt f32x4 stores ----
  const long long rl = (long long)r;
#pragma unroll
  for (int t = 0; t < 16; ++t) {
    const int srcRow = 4 * t + (lane >> 4);            // 0..63 within the wave
    const uint64_t b = (uint64_t)__shfl(rl, srcRow, 64);
    const int c0 = (lane & 15) * 4;                    // pulse index of o.x
    f32x4 o;
    o.x = (float)((b >> (63 - c0)) & 1ULL);
    o.y = (float)((b >> (62 - c0)) & 1ULL);
    o.z = (float)((b >> (61 - c0)) & 1ULL);
    o.w = (float)((b >> (60 - c0)) & 1ULL);
    const long long row = waveRow0 + srcRow;
    if (row < (long long)rows) {
      // 1KB contiguous per instr (full 128B lines), non-temporal
      __builtin_nontemporal_store(o, reinterpret_cast<f32x4*>(out + row * 64 + c0));
    }
  }
}

extern "C" void kernel_launch(void* const* d_in, const int* in_sizes, int n_in,
                              void* d_out, int out_size, void* d_ws, size_t ws_size,
                              hipStream_t stream) {
  const float* x = (const float*)d_in[0];
  float* out = (float*)d_out;
  (void)d_ws; (void)ws_size;
  const int rows = in_sizes[0] / 64;                   // 64 pulses per fp64
  const int rowsPerBlock = 256;                        // 4 waves * 64 rows
  const int grid = (rows + rowsPerBlock - 1) / rowsPerBlock;
  spike_sqrt_fused_kernel<<<grid, 256, 0, stream>>>(x, out, rows);
}